// Round 1
// baseline (30026.559 us; speedup 1.0000x reference)
//
#include <hip/hip_runtime.h>
#include <hip/hip_bf16.h>

#define T_ 256
#define B_ 128
#define H_ 512
#define G3 1536   // 3*H

typedef __attribute__((ext_vector_type(8))) short short8;
typedef __attribute__((ext_vector_type(4))) short short4v;
typedef __attribute__((ext_vector_type(4))) float f32x4;

static __device__ __forceinline__ float b2f(short s){
    unsigned u = ((unsigned)(unsigned short)s) << 16;
    return __builtin_bit_cast(float, u);
}
static __device__ __forceinline__ short f2b(float f){
    __hip_bfloat16 h = __float2bfloat16(f);   // RNE
    return __builtin_bit_cast(short, h);
}

// ---------------- fp32 -> bf16 weight conversion ----------------
__global__ void cvt_f32_to_bf16(const float* __restrict__ src, short* __restrict__ dst, int n){
    int i = (blockIdx.x * blockDim.x + threadIdx.x) * 4;
    int stride = gridDim.x * blockDim.x * 4;
    for (; i + 3 < n; i += stride){
        float4 v = *(const float4*)(src + i);
        short4v o;
        o[0] = f2b(v.x); o[1] = f2b(v.y); o[2] = f2b(v.z); o[3] = f2b(v.w);
        *(short4v*)(dst + i) = o;
    }
}

// ---------------- fused GRU step (both directions) ----------------
// grid = (8 unit-groups, 4 batch-groups, 2 directions), block = 256 (4 waves)
// WG: 32 batch rows x 64 hidden units x 3 gates. A (x_t, h) staged in LDS,
// B (weights) streamed global(L2)->reg. Separate x/h accumulators (n-gate needs it).
__global__ __launch_bounds__(256, 1) void gru_step(
    const void* __restrict__ x_in, int x_f32, int Cin,
    const short* __restrict__ Wih,   // [2][1536][Cin] bf16
    const short* __restrict__ Whh,   // [2][1536][512] bf16
    const float* __restrict__ bih,   // [2][1536]
    const float* __restrict__ bhh,   // [2][1536]
    float* __restrict__ hf,          // [2][128][512] fp32 master h
    short* __restrict__ hb,          // [2][128][512] bf16 h (GEMM operand)
    short* __restrict__ x_out,       // [256][128][1024] bf16 layer output
    int s)
{
    __shared__ short lds_x[32 * 1032];   // stride Cin+8 (pad keeps 16B align, 2-way banks = free)
    __shared__ short lds_h[32 * 520];

    const int tid = threadIdx.x;
    const int ug = blockIdx.x, bg = blockIdx.y, dir = blockIdx.z;
    const int t = dir ? (T_ - 1 - s) : s;
    const int row0 = bg * 32;
    const int LXS = Cin + 8;

    // ---- stage x_t rows [row0, row0+32) into LDS (convert fp32->bf16 for layer 0)
    {
        const int cpr = Cin / 8;               // 16B chunks per row
        const int total = 32 * cpr;
        for (int c = tid; c < total; c += 256){
            int r = c / cpr, kc = (c % cpr) * 8;
            size_t g = ((size_t)t * B_ + row0 + r) * Cin + kc;
            short8 v;
            if (x_f32){
                const float* xp = (const float*)x_in + g;
                float4 a = *(const float4*)xp;
                float4 b = *(const float4*)(xp + 4);
                v[0]=f2b(a.x); v[1]=f2b(a.y); v[2]=f2b(a.z); v[3]=f2b(a.w);
                v[4]=f2b(b.x); v[5]=f2b(b.y); v[6]=f2b(b.z); v[7]=f2b(b.w);
            } else {
                v = *(const short8*)((const short*)x_in + g);
            }
            *(short8*)&lds_x[r * LXS + kc] = v;
        }
    }
    // ---- stage h rows into LDS
    for (int c = tid; c < 32 * 64; c += 256){
        int r = c >> 6, kc = (c & 63) * 8;
        size_t g = ((size_t)dir * B_ + row0 + r) * H_ + kc;
        *(short8*)&lds_h[r * 520 + kc] = *(const short8*)(hb + g);
    }
    __syncthreads();

    const int wid = tid >> 6, lane = tid & 63;
    const int u0 = ug * 64 + wid * 16;     // this wave's 16 hidden units
    const int lr = lane & 15;              // A row within tile / B col within tile
    const int lk = (lane >> 4) * 8;        // k offset within K=32 slice

    f32x4 accx[2][3] = {{{0.f,0.f,0.f,0.f},{0.f,0.f,0.f,0.f},{0.f,0.f,0.f,0.f}},
                        {{0.f,0.f,0.f,0.f},{0.f,0.f,0.f,0.f},{0.f,0.f,0.f,0.f}}};
    f32x4 acch[2][3] = {{{0.f,0.f,0.f,0.f},{0.f,0.f,0.f,0.f},{0.f,0.f,0.f,0.f}},
                        {{0.f,0.f,0.f,0.f},{0.f,0.f,0.f,0.f},{0.f,0.f,0.f,0.f}}};

    // ---- x-side GEMM: K = Cin
    const short* WihD = Wih + (size_t)dir * G3 * Cin;
    #pragma unroll 2
    for (int k0 = 0; k0 < Cin; k0 += 32){
        short8 a0 = *(const short8*)&lds_x[(lr)      * LXS + k0 + lk];
        short8 a1 = *(const short8*)&lds_x[(16 + lr) * LXS + k0 + lk];
        #pragma unroll
        for (int g = 0; g < 3; ++g){
            short8 b = *(const short8*)&WihD[((size_t)(g * H_ + u0 + lr)) * Cin + k0 + lk];
            accx[0][g] = __builtin_amdgcn_mfma_f32_16x16x32_bf16(a0, b, accx[0][g], 0, 0, 0);
            accx[1][g] = __builtin_amdgcn_mfma_f32_16x16x32_bf16(a1, b, accx[1][g], 0, 0, 0);
        }
    }
    // ---- h-side GEMM: K = 512
    const short* WhhD = Whh + (size_t)dir * G3 * H_;
    #pragma unroll 2
    for (int k0 = 0; k0 < H_; k0 += 32){
        short8 a0 = *(const short8*)&lds_h[(lr)      * 520 + k0 + lk];
        short8 a1 = *(const short8*)&lds_h[(16 + lr) * 520 + k0 + lk];
        #pragma unroll
        for (int g = 0; g < 3; ++g){
            short8 b = *(const short8*)&WhhD[((size_t)(g * H_ + u0 + lr)) * H_ + k0 + lk];
            acch[0][g] = __builtin_amdgcn_mfma_f32_16x16x32_bf16(a0, b, acch[0][g], 0, 0, 0);
            acch[1][g] = __builtin_amdgcn_mfma_f32_16x16x32_bf16(a1, b, acch[1][g], 0, 0, 0);
        }
    }

    // ---- gates: triplet (r,z,n) for unit u is in the SAME lane across acc tiles
    const int u = u0 + lr;
    const float bir = bih[dir*G3 + u], biz = bih[dir*G3 + 512 + u], bin = bih[dir*G3 + 1024 + u];
    const float bhr = bhh[dir*G3 + u], bhz = bhh[dir*G3 + 512 + u], bhn = bhh[dir*G3 + 1024 + u];
    #pragma unroll
    for (int mt = 0; mt < 2; ++mt){
        #pragma unroll
        for (int r = 0; r < 4; ++r){
            int m = row0 + mt*16 + ((lane >> 4) << 2) + r;   // C/D row mapping (m89)
            float xr = accx[mt][0][r] + bir;
            float xz = accx[mt][1][r] + biz;
            float xn = accx[mt][2][r] + bin;
            float hr = acch[mt][0][r] + bhr;
            float hz = acch[mt][1][r] + bhz;
            float hn = acch[mt][2][r] + bhn;
            float rg = 1.f / (1.f + __expf(-(xr + hr)));
            float zg = 1.f / (1.f + __expf(-(xz + hz)));
            float ng = tanhf(xn + rg * hn);
            size_t hidx = ((size_t)dir * B_ + m) * H_ + u;
            float hp = hf[hidx];
            float hnew = (1.f - zg) * ng + zg * hp;
            hf[hidx] = hnew;
            short h16 = f2b(hnew);
            hb[hidx] = h16;
            x_out[((size_t)t * B_ + m) * 1024 + dir * H_ + u] = h16;
        }
    }
}

// ---------------- final FC + sigmoid ----------------
// one wave per (t,b): dot(h[t,b,:1024], fc_w) + fc_b -> sigmoid
__global__ void fc_kernel(const short* __restrict__ h, const float* __restrict__ w,
                          const float* __restrict__ b, float* __restrict__ out){
    int wid = threadIdx.x >> 6, lane = threadIdx.x & 63;
    int tb = blockIdx.x * 4 + wid;
    const short* hp = h + (size_t)tb * 1024 + lane * 16;
    float s = 0.f;
    #pragma unroll
    for (int c = 0; c < 2; ++c){
        short8 v = *(const short8*)(hp + c * 8);
        #pragma unroll
        for (int e = 0; e < 8; ++e) s += b2f(v[e]) * w[lane * 16 + c * 8 + e];
    }
    #pragma unroll
    for (int o = 32; o; o >>= 1) s += __shfl_down(s, o);
    if (lane == 0) out[tb] = 1.f / (1.f + __expf(-(s + b[0])));
}

extern "C" void kernel_launch(void* const* d_in, const int* in_sizes, int n_in,
                              void* d_out, int out_size, void* d_ws, size_t ws_size,
                              hipStream_t stream){
    const float* input_seq = (const float*)d_in[0];
    const float* W_ih0 = (const float*)d_in[1];
    const float* W_hh0 = (const float*)d_in[2];
    const float* b_ih0 = (const float*)d_in[3];
    const float* b_hh0 = (const float*)d_in[4];
    const float* W_ih  = (const float*)d_in[5];
    const float* W_hh  = (const float*)d_in[6];
    const float* b_ih  = (const float*)d_in[7];
    const float* b_hh  = (const float*)d_in[8];
    const float* fc_w  = (const float*)d_in[9];
    const float* fc_b  = (const float*)d_in[10];

    char* ws = (char*)d_ws;
    size_t off = 0;
    auto alloc = [&](size_t bytes) -> char* {
        char* p = ws + off; off += (bytes + 255) & ~(size_t)255; return p;
    };
    short* wih0b = (short*)alloc((size_t)2*G3*128 * 2);
    short* whh0b = (short*)alloc((size_t)2*G3*H_  * 2);
    short* wihb  = (short*)alloc((size_t)4*2*G3*1024 * 2);
    short* whhb  = (short*)alloc((size_t)4*2*G3*H_   * 2);
    short* bufA  = (short*)alloc((size_t)T_*B_*1024 * 2);
    short* bufB  = (short*)alloc((size_t)T_*B_*1024 * 2);
    float* hf    = (float*)alloc((size_t)2*B_*H_ * 4);
    short* hb    = (short*)alloc((size_t)2*B_*H_ * 2);
    (void)ws_size; (void)in_sizes; (void)n_in; (void)out_size;

    auto cvt = [&](const float* s, short* d, size_t n){
        int blocks = (int)((n/4 + 255) / 256); if (blocks > 4096) blocks = 4096;
        hipLaunchKernelGGL(cvt_f32_to_bf16, dim3(blocks), dim3(256), 0, stream, s, d, (int)n);
    };
    cvt(W_ih0, wih0b, (size_t)2*G3*128);
    cvt(W_hh0, whh0b, (size_t)2*G3*H_);
    cvt(W_ih,  wihb,  (size_t)4*2*G3*1024);
    cvt(W_hh,  whhb,  (size_t)4*2*G3*H_);

    for (int l = 0; l < 5; ++l){
        // zero h master (fp32) + h bf16 (they are adjacent allocations)
        hipMemsetAsync(hf, 0, (size_t)2*B_*H_*4, stream);
        hipMemsetAsync(hb, 0, (size_t)2*B_*H_*2, stream);

        const void* xin; int xf32, Cin;
        const short *wih_l, *whh_l;
        const float *bih_l, *bhh_l;
        short* outb = (l & 1) ? bufB : bufA;
        if (l == 0){
            xin = (const void*)input_seq; xf32 = 1; Cin = 128;
            wih_l = wih0b; whh_l = whh0b; bih_l = b_ih0; bhh_l = b_hh0;
        } else {
            xin = (const void*)((l & 1) ? bufA : bufB); xf32 = 0; Cin = 1024;
            wih_l = wihb + (size_t)(l-1)*2*G3*1024;
            whh_l = whhb + (size_t)(l-1)*2*G3*H_;
            bih_l = b_ih + (size_t)(l-1)*2*G3;
            bhh_l = b_hh + (size_t)(l-1)*2*G3;
        }
        for (int s = 0; s < T_; ++s){
            hipLaunchKernelGGL(gru_step, dim3(8,4,2), dim3(256), 0, stream,
                               xin, xf32, Cin, wih_l, whh_l, bih_l, bhh_l,
                               hf, hb, outb, s);
        }
    }
    // layer 4 output is bufA
    hipLaunchKernelGGL(fc_kernel, dim3((T_*B_)/4), dim3(256), 0, stream,
                       bufA, fc_w, fc_b, (float*)d_out);
}